// Round 1
// baseline (41545.300 us; speedup 1.0000x reference)
//
#include <hip/hip_runtime.h>
#include <hip/hip_bf16.h>
#include <math.h>

#define BATCH 128
#define QD 88
#define HDIM 512
#define ZDIM 1280
#define GDIM 2048
#define STATE_IN 95
#define OFF_IN 91
#define OUTD 95
#define NPAST 10
#define NTRANS 29
#define POSE_ELEMS (BATCH * 30 * 91)   // 349440

__device__ __forceinline__ float sig_(float x) { return 1.0f / (1.0f + expf(-x)); }

// One block per batch sample. The whole 39-step recurrence runs inside the
// block; all carry state lives in LDS so no inter-block sync is needed.
// block = 1024 threads (16 waves): waves each own 128 rows of the 2048-row
// per-sample hypernetwork matvec (the HBM-dominant part).
extern "C" __global__ void __launch_bounds__(1024)
etn_kernel(const float* __restrict__ past_root_vel,    // [B,10,3]
           const float* __restrict__ past_quats,       // [B,10,88]
           const float* __restrict__ past_root_offset, // [B,10,3]
           const float* __restrict__ past_quat_offset, // [B,10,88]
           const float* __restrict__ past_contacts,    // [B,10,4]
           const float* __restrict__ target_root_pos,  // [B,3]
           const float* __restrict__ target_quats,     // [B,88]
           const float* __restrict__ init_root_pos,    // [B,3]
           const float* __restrict__ pred_weights,     // [B,2048,1280]
           const float* __restrict__ pred_bias,        // [B,2048]
           const float* __restrict__ se_w1, const float* __restrict__ se_b1,
           const float* __restrict__ se_w2, const float* __restrict__ se_b2,
           const float* __restrict__ oe_w1, const float* __restrict__ oe_b1,
           const float* __restrict__ oe_w2, const float* __restrict__ oe_b2,
           const float* __restrict__ te_w1, const float* __restrict__ te_b1,
           const float* __restrict__ te_w2, const float* __restrict__ te_b2,
           const float* __restrict__ de_w1, const float* __restrict__ de_b1,
           const float* __restrict__ de_w2, const float* __restrict__ de_b2,
           const float* __restrict__ de_w3, const float* __restrict__ de_b3,
           float* __restrict__ out)
{
    const int b = blockIdx.x;
    const int t = threadIdx.x;

    __shared__ __align__(16) float z[ZDIM];   // [h_state 256 | h_off 256 | h_tgt 256 | h 512]
    __shared__ float gates[GDIM];
    __shared__ float cst[HDIM];
    __shared__ float bufA[512];
    __shared__ float bufB[512];
    __shared__ float d2buf[256];
    __shared__ float sv[STATE_IN];   // [contacts 4 | quats 88 | rvel 3]
    __shared__ float ov[OFF_IN];     // [roff 3 | qoff 88]
    __shared__ float outv[OUTD];
    __shared__ float quats_s[QD], qoff_s[QD], nq_s[QD], tq_s[QD];
    __shared__ float rvel_s[3], roff_s[3], glob_s[3], trp_s[3], cont_s[4];

    // ---- init carry ----
    if (t < HDIM) { cst[t] = 0.f; z[768 + t] = 0.f; }
    if (t < QD)   { tq_s[t] = target_quats[b * QD + t]; quats_s[t] = 0.f; qoff_s[t] = 0.f; }
    if (t < 3)    { glob_s[t] = init_root_pos[b * 3 + t];
                    trp_s[t]  = target_root_pos[b * 3 + t];
                    rvel_s[t] = 0.f; roff_s[t] = 0.f; }
    if (t < 4)    cont_s[t] = 0.f;
    __syncthreads();

    // ---- h_target (hoisted): enc(target_quats) -> z[512:768] ----
    if (t < 512) {
        float acc = te_b1[t];
        for (int i = 0; i < QD; ++i) acc += tq_s[i] * te_w1[i * 512 + t];
        bufA[t] = fmaxf(acc, 0.f);
    }
    __syncthreads();
    if (t < 256) {
        float acc = te_b2[t];
        for (int i = 0; i < 512; ++i) acc += bufA[i] * te_w2[i * 256 + t];
        z[512 + t] = fmaxf(acc, 0.f);
    }

    // ---- 39 sequential steps ----
    for (int s = 0; s < NPAST + NTRANS; ++s) {
        __syncthreads();
        const bool past = (s < NPAST);
        // build state_vec / offset_vec
        if (past) {
            if (t < 4)  sv[t]      = past_contacts[(b * NPAST + s) * 4 + t];
            if (t < QD) { sv[4 + t] = past_quats[(b * NPAST + s) * QD + t];
                          ov[3 + t] = past_quat_offset[(b * NPAST + s) * QD + t]; }
            if (t < 3)  { sv[92 + t] = past_root_vel[(b * NPAST + s) * 3 + t];
                          ov[t]      = past_root_offset[(b * NPAST + s) * 3 + t]; }
        } else {
            if (t < 4)  sv[t] = cont_s[t];
            if (t < QD) { sv[4 + t] = quats_s[t]; ov[3 + t] = qoff_s[t]; }
            if (t < 3)  { sv[92 + t] = rvel_s[t]; ov[t] = roff_s[t]; }
        }
        __syncthreads();

        // encoders layer 1 (state: threads 0..511, offset: threads 512..1023)
        if (t < 512) {
            float acc = se_b1[t];
            for (int i = 0; i < STATE_IN; ++i) acc += sv[i] * se_w1[i * 512 + t];
            bufA[t] = fmaxf(acc, 0.f);
        } else {
            const int tt = t - 512;
            float acc = oe_b1[tt];
            for (int i = 0; i < OFF_IN; ++i) acc += ov[i] * oe_w1[i * 512 + tt];
            bufB[tt] = fmaxf(acc, 0.f);
        }
        __syncthreads();
        // encoders layer 2 -> z[0:256], z[256:512]
        if (t < 256) {
            float acc = se_b2[t];
            for (int i = 0; i < 512; ++i) acc += bufA[i] * se_w2[i * 256 + t];
            z[t] = fmaxf(acc, 0.f);
        } else if (t < 512) {
            const int tt = t - 256;
            float acc = oe_b2[tt];
            for (int i = 0; i < 512; ++i) acc += bufB[i] * oe_w2[i * 256 + tt];
            z[256 + tt] = fmaxf(acc, 0.f);
        }
        __syncthreads();

        // hypernetwork gate matvec: gates[o] = W[b,o,:] . z + bias  (HBM-dominant)
        {
            const int wave = t >> 6, lane = t & 63;
            float4 zv[5];
#pragma unroll
            for (int k = 0; k < 5; ++k)
                zv[k] = *reinterpret_cast<const float4*>(&z[4 * (lane + 64 * k)]);
            const float* wb = pred_weights + (size_t)b * GDIM * ZDIM;
            const int o0 = wave * 128;
            for (int r = 0; r < 128; ++r) {
                const int o = o0 + r;
                const float* wr = wb + (size_t)o * ZDIM;
                float acc = 0.f;
#pragma unroll
                for (int k = 0; k < 5; ++k) {
                    const float4 wv = *reinterpret_cast<const float4*>(&wr[4 * (lane + 64 * k)]);
                    acc += wv.x * zv[k].x + wv.y * zv[k].y + wv.z * zv[k].z + wv.w * zv[k].w;
                }
#pragma unroll
                for (int m = 32; m >= 1; m >>= 1) acc += __shfl_xor(acc, m, 64);
                if (lane == 0) gates[o] = acc + pred_bias[b * GDIM + o];
            }
        }
        __syncthreads();

        // LSTM cell (torch gate order i,f,g,o); h2 -> z[768:1280]
        if (t < HDIM) {
            const float ig = gates[t], fg = gates[512 + t];
            const float gg = gates[1024 + t], og = gates[1536 + t];
            const float c2 = sig_(fg) * cst[t] + sig_(ig) * tanhf(gg);
            cst[t] = c2;
            z[768 + t] = sig_(og) * tanhf(c2);
        }
        __syncthreads();

        // decoder: 512 -> 512 -> 256 -> 95
        if (t < 512) {
            float acc = de_b1[t];
            for (int i = 0; i < 512; ++i) acc += z[768 + i] * de_w1[i * 512 + t];
            bufA[t] = fmaxf(acc, 0.f);
        }
        __syncthreads();
        if (t < 256) {
            float acc = de_b2[t];
            for (int i = 0; i < 512; ++i) acc += bufA[i] * de_w2[i * 256 + t];
            d2buf[t] = fmaxf(acc, 0.f);
        }
        __syncthreads();
        if (t < OUTD) {
            float acc = de_b3[t];
            for (int i = 0; i < 256; ++i) acc += d2buf[i] * de_w3[i * OUTD + t];
            outv[t] = acc;
        }
        __syncthreads();

        // next_quats = out[:88] + quats_in, then per-4 normalize
        if (t < QD) nq_s[t] = outv[t] + sv[4 + t];
        __syncthreads();
        if (t < 22) {
            const float a = nq_s[4 * t], b2 = nq_s[4 * t + 1];
            const float c3 = nq_s[4 * t + 2], d4 = nq_s[4 * t + 3];
            const float inv = 1.f / fmaxf(sqrtf(a * a + b2 * b2 + c3 * c3 + d4 * d4), 1e-12f);
            nq_s[4 * t] = a * inv; nq_s[4 * t + 1] = b2 * inv;
            nq_s[4 * t + 2] = c3 * inv; nq_s[4 * t + 3] = d4 * inv;
        }
        __syncthreads();

        // carry updates
        if (t < 3) {
            const float nrv = outv[88 + t] + sv[92 + t];       // out + input rvel
            const float g = glob_s[t] + (past ? sv[92 + t] : nrv); // past: +input rvel; trans: +new rvel
            glob_s[t] = g;
            rvel_s[t] = nrv;
            roff_s[t] = g - trp_s[t];
        }
        if (t < 4) cont_s[t] = sig_(outv[91 + t]);
        if (t < QD) { quats_s[t] = nq_s[t]; qoff_s[t] = nq_s[t] - tq_s[t]; }
        __syncthreads();

        // outputs
        if (!past) {
            const int k = s - NPAST + 1;               // frames 1..29
            const size_t pbase = ((size_t)b * 30 + k) * 91;
            if (t < 3)  out[pbase + t] = glob_s[t];
            if (t < QD) out[pbase + 3 + t] = nq_s[t];
            if (t < 4)  out[POSE_ELEMS + ((size_t)b * 30 + k) * 4 + t] = cont_s[t];
        } else if (s == NPAST - 1) {
            // first frame = [nrv, nq] (rvel, not glob — as in source)
            const size_t pbase = (size_t)b * 30 * 91;
            if (t < 3)  out[pbase + t] = rvel_s[t];
            if (t < QD) out[pbase + 3 + t] = quats_s[t];
            if (t < 4)  out[POSE_ELEMS + (size_t)b * 30 * 4 + t] = cont_s[t];
        }
    }
}

extern "C" void kernel_launch(void* const* d_in, const int* in_sizes, int n_in,
                              void* d_out, int out_size, void* d_ws, size_t ws_size,
                              hipStream_t stream) {
    etn_kernel<<<dim3(BATCH), dim3(1024), 0, stream>>>(
        (const float*)d_in[0],  (const float*)d_in[1],  (const float*)d_in[2],
        (const float*)d_in[3],  (const float*)d_in[4],  (const float*)d_in[5],
        (const float*)d_in[6],  (const float*)d_in[7],  (const float*)d_in[8],
        (const float*)d_in[9],
        (const float*)d_in[10], (const float*)d_in[11], (const float*)d_in[12], (const float*)d_in[13],
        (const float*)d_in[14], (const float*)d_in[15], (const float*)d_in[16], (const float*)d_in[17],
        (const float*)d_in[18], (const float*)d_in[19], (const float*)d_in[20], (const float*)d_in[21],
        (const float*)d_in[22], (const float*)d_in[23], (const float*)d_in[24], (const float*)d_in[25],
        (const float*)d_in[26], (const float*)d_in[27],
        (float*)d_out);
}

// Round 3
// 12126.716 us; speedup vs baseline: 3.4259x; 3.4259x over previous
//
#include <hip/hip_runtime.h>
#include <hip/hip_bf16.h>
#include <math.h>

#define BATCH 128
#define QD 88
#define HDIM 512
#define ZDIM 1280
#define GDIM 2048
#define NPAST 10
#define NTRANS 29
#define NSTEPS (NPAST + NTRANS)
#define OUTD 95
#define POSE_ELEMS (BATCH * 30 * 91)

__device__ __forceinline__ float sig_(float x) { return 1.0f / (1.0f + expf(-x)); }
__device__ __forceinline__ float bflo_(unsigned u) { return __uint_as_float(u << 16); }
__device__ __forceinline__ float bfhi_(unsigned u) { return __uint_as_float(u & 0xffff0000u); }

__device__ __forceinline__ void dot8_(const uint4 wv, const float4 za, const float4 zb,
                                      float& d) {
    d = fmaf(bflo_(wv.x), za.x, d); d = fmaf(bfhi_(wv.x), za.y, d);
    d = fmaf(bflo_(wv.y), za.z, d); d = fmaf(bfhi_(wv.y), za.w, d);
    d = fmaf(bflo_(wv.z), zb.x, d); d = fmaf(bfhi_(wv.z), zb.y, d);
    d = fmaf(bflo_(wv.w), zb.z, d); d = fmaf(bfhi_(wv.w), zb.w, d);
}
__device__ __forceinline__ void dot4_(const uint4 wv, const float4 zv, float& d) {
    const float4 f = *(const float4*)&wv;
    d = fmaf(f.x, zv.x, d); d = fmaf(f.y, zv.y, d);
    d = fmaf(f.z, zv.z, d); d = fmaf(f.w, zv.w, d);
}

// ---------------- fp32 -> bf16 (RNE) weight conversion, once per call ----------------
__global__ void __launch_bounds__(256)
conv_bf16(const float4* __restrict__ in, uint4* __restrict__ out, int n8)
{
    const int stride = gridDim.x * 256;
    for (int i = blockIdx.x * 256 + threadIdx.x; i < n8; i += stride) {
        const float4 a = in[2 * i], b = in[2 * i + 1];
        uint4 o;
        #define BF_(f) ((__float_as_uint(f) + 0x7fffu + ((__float_as_uint(f) >> 16) & 1u)) >> 16)
        o.x = BF_(a.x) | (BF_(a.y) << 16);
        o.y = BF_(a.z) | (BF_(a.w) << 16);
        o.z = BF_(b.x) | (BF_(b.y) << 16);
        o.w = BF_(b.z) | (BF_(b.w) << 16);
        #undef BF_
        out[i] = o;
    }
}

// ---------------- per-step hypernetwork GEMV, bf16 weights ----------------
// grid 4096 = 128 samples x 32 chunks; block 256 = 4 waves; wave: 16 rows (8 pairs)
__global__ void __launch_bounds__(256)
matvec_bf16(const unsigned short* __restrict__ W, const float* __restrict__ z_ws,
            float* __restrict__ g_ws)
{
    const int b = blockIdx.x >> 5, chunk = blockIdx.x & 31;
    const int wave = threadIdx.x >> 6, lane = threadIdx.x & 63;
    const int row0 = chunk * 64 + wave * 16;
    const float* zb = z_ws + b * ZDIM;
    const int l8 = lane * 8;
    // pair-element idx for slot k = k*512 + lane*8 (mod 1280 for slot 2)
    int e2 = 1024 + l8; if (e2 >= ZDIM) e2 -= ZDIM;
    const float4 zA0 = *(const float4*)(zb + l8),        zB0 = *(const float4*)(zb + l8 + 4);
    const float4 zA1 = *(const float4*)(zb + 512 + l8),  zB1 = *(const float4*)(zb + 512 + l8 + 4);
    const float4 zA2 = *(const float4*)(zb + e2),        zB2 = *(const float4*)(zb + e2 + 4);
    const float4 zA3 = *(const float4*)(zb + 256 + l8),  zB3 = *(const float4*)(zb + 256 + l8 + 4);
    const float4 zA4 = *(const float4*)(zb + 768 + l8),  zB4 = *(const float4*)(zb + 768 + l8 + 4);
    const char* wb = (const char*)W + (size_t)b * GDIM * ZDIM * 2;

    #define ISSUE(p, B) { const char* a_ = wb + (size_t)(row0 + 2 * (p)) * (ZDIM * 2) + lane * 16; \
        B[0] = *(const uint4*)(a_);        B[1] = *(const uint4*)(a_ + 1024); \
        B[2] = *(const uint4*)(a_ + 2048); B[3] = *(const uint4*)(a_ + 3072); \
        B[4] = *(const uint4*)(a_ + 4096); }

    uint4 bufa[5], bufb[5];
    ISSUE(0, bufa);
    #pragma unroll
    for (int p = 0; p < 8; ++p) {
        uint4* cur = (p & 1) ? bufb : bufa;
        uint4* nxt = (p & 1) ? bufa : bufb;
        if (p < 7) ISSUE(p + 1, nxt);
        float accA = 0.f, accB = 0.f, mid = 0.f;
        dot8_(cur[0], zA0, zB0, accA);
        dot8_(cur[1], zA1, zB1, accA);
        dot8_(cur[2], zA2, zB2, mid);
        dot8_(cur[3], zA3, zB3, accB);
        dot8_(cur[4], zA4, zB4, accB);
        if (lane < 32) accA += mid; else accB += mid;
        float s0 = accA + __shfl_xor(accA, 32);
        float s1 = accB + __shfl_xor(accB, 32);
        float u = (lane < 32) ? s0 : s1;
        #pragma unroll
        for (int m = 16; m >= 1; m >>= 1) u += __shfl_xor(u, m);
        if (lane == 0)       g_ws[b * GDIM + row0 + 2 * p]     = u;
        else if (lane == 32) g_ws[b * GDIM + row0 + 2 * p + 1] = u;
    }
    #undef ISSUE
}

// ---------------- per-step hypernetwork GEMV, fp32 weights (ws fallback) ----------------
__global__ void __launch_bounds__(256)
matvec_f32(const float* __restrict__ W, const float* __restrict__ z_ws, float* __restrict__ g_ws)
{
    const int b = blockIdx.x >> 5, chunk = blockIdx.x & 31;
    const int wave = threadIdx.x >> 6, lane = threadIdx.x & 63;
    const int row0 = chunk * 64 + wave * 16;
    const float* zb = z_ws + b * ZDIM;
    const int l4 = lane * 4;
    const float4 z0 = *(const float4*)(zb + l4);
    const float4 z1 = *(const float4*)(zb + 256 + l4);
    const float4 z2 = *(const float4*)(zb + 512 + l4);
    const float4 z3 = *(const float4*)(zb + 768 + l4);
    const float4 z4 = *(const float4*)(zb + 1024 + l4);
    const char* wb = (const char*)W + (size_t)b * GDIM * ZDIM * 4;

    #define ISSUE(p, B) { const char* a_ = wb + (size_t)(row0 + 2 * (p)) * (ZDIM * 4) + lane * 16; \
        _Pragma("unroll") for (int i = 0; i < 10; ++i) B[i] = *(const uint4*)(a_ + i * 1024); }

    uint4 bufa[10], bufb[10];
    ISSUE(0, bufa);
    #pragma unroll
    for (int p = 0; p < 8; ++p) {
        uint4* cur = (p & 1) ? bufb : bufa;
        uint4* nxt = (p & 1) ? bufa : bufb;
        if (p < 7) ISSUE(p + 1, nxt);
        float accA = 0.f, accB = 0.f;
        dot4_(cur[0], z0, accA); dot4_(cur[1], z1, accA); dot4_(cur[2], z2, accA);
        dot4_(cur[3], z3, accA); dot4_(cur[4], z4, accA);
        dot4_(cur[5], z0, accB); dot4_(cur[6], z1, accB); dot4_(cur[7], z2, accB);
        dot4_(cur[8], z3, accB); dot4_(cur[9], z4, accB);
        float s0 = accA + __shfl_xor(accA, 32);
        float s1 = accB + __shfl_xor(accB, 32);
        float u = (lane < 32) ? s0 : s1;
        #pragma unroll
        for (int m = 16; m >= 1; m >>= 1) u += __shfl_xor(u, m);
        if (lane == 0)       g_ws[b * GDIM + row0 + 2 * p]     = u;
        else if (lane == 32) g_ws[b * GDIM + row0 + 2 * p + 1] = u;
    }
    #undef ISSUE
}

// ---------------- init: state=0, h_target, step-0 encoders ----------------
__global__ void __launch_bounds__(512)
initk(const float* __restrict__ past_root_vel, const float* __restrict__ past_quats,
      const float* __restrict__ past_root_offset, const float* __restrict__ past_quat_offset,
      const float* __restrict__ past_contacts, const float* __restrict__ target_quats,
      const float* __restrict__ init_root_pos,
      const float* __restrict__ se_w1, const float* __restrict__ se_b1,
      const float* __restrict__ se_w2, const float* __restrict__ se_b2,
      const float* __restrict__ oe_w1, const float* __restrict__ oe_b1,
      const float* __restrict__ oe_w2, const float* __restrict__ oe_b2,
      const float* __restrict__ te_w1, const float* __restrict__ te_b1,
      const float* __restrict__ te_w2, const float* __restrict__ te_b2,
      float* __restrict__ z_ws, float* __restrict__ c_ws, float* __restrict__ car_ws)
{
    const int b = blockIdx.x, t = threadIdx.x;
    __shared__ float tq[QD], bufA[512], bufB[512], sv[95], ov[91];

    if (t < 192) car_ws[b * 192 + t] = (t < 3) ? init_root_pos[b * 3 + t] : 0.f;
    c_ws[b * HDIM + t] = 0.f;
    z_ws[b * ZDIM + 768 + t] = 0.f;
    if (t < QD) tq[t] = target_quats[b * QD + t];
    if (t < 4)  sv[t] = past_contacts[b * NPAST * 4 + t];
    if (t < QD) { sv[4 + t] = past_quats[b * NPAST * QD + t];
                  ov[3 + t] = past_quat_offset[b * NPAST * QD + t]; }
    if (t < 3)  { sv[92 + t] = past_root_vel[b * NPAST * 3 + t];
                  ov[t]      = past_root_offset[b * NPAST * 3 + t]; }
    __syncthreads();
    // h_target
    {
        float a = te_b1[t];
        #pragma unroll 4
        for (int i = 0; i < QD; ++i) a = fmaf(tq[i], te_w1[i * 512 + t], a);
        bufA[t] = fmaxf(a, 0.f);
    }
    __syncthreads();
    if (t < 256) {
        float a = te_b2[t];
        #pragma unroll 4
        for (int i = 0; i < 512; ++i) a = fmaf(bufA[i], te_w2[i * 256 + t], a);
        z_ws[b * ZDIM + 512 + t] = fmaxf(a, 0.f);
    }
    __syncthreads();
    // step-0 encoders
    {
        float aS = se_b1[t], aO = oe_b1[t];
        #pragma unroll 4
        for (int i = 0; i < 91; ++i) { aS = fmaf(sv[i], se_w1[i * 512 + t], aS);
                                       aO = fmaf(ov[i], oe_w1[i * 512 + t], aO); }
        #pragma unroll
        for (int i = 91; i < 95; ++i) aS = fmaf(sv[i], se_w1[i * 512 + t], aS);
        bufA[t] = fmaxf(aS, 0.f);
        bufB[t] = fmaxf(aO, 0.f);
    }
    __syncthreads();
    if (t < 256) {
        float a = se_b2[t];
        #pragma unroll 4
        for (int i = 0; i < 512; ++i) a = fmaf(bufA[i], se_w2[i * 256 + t], a);
        z_ws[b * ZDIM + t] = fmaxf(a, 0.f);
    } else {
        const int j = t - 256;
        float a = oe_b2[j];
        #pragma unroll 4
        for (int i = 0; i < 512; ++i) a = fmaf(bufB[i], oe_w2[i * 256 + j], a);
        z_ws[b * ZDIM + 256 + j] = fmaxf(a, 0.f);
    }
}

// ---------------- per-step: LSTM + decoder + state update + next encoders ----------------
__global__ void __launch_bounds__(512)
stepk(const float* __restrict__ past_root_vel, const float* __restrict__ past_quats,
      const float* __restrict__ past_root_offset, const float* __restrict__ past_quat_offset,
      const float* __restrict__ past_contacts, const float* __restrict__ target_root_pos,
      const float* __restrict__ target_quats, const float* __restrict__ pred_bias,
      const float* __restrict__ se_w1, const float* __restrict__ se_b1,
      const float* __restrict__ se_w2, const float* __restrict__ se_b2,
      const float* __restrict__ oe_w1, const float* __restrict__ oe_b1,
      const float* __restrict__ oe_w2, const float* __restrict__ oe_b2,
      const float* __restrict__ de_w1, const float* __restrict__ de_b1,
      const float* __restrict__ de_w2, const float* __restrict__ de_b2,
      const float* __restrict__ de_w3, const float* __restrict__ de_b3,
      float* __restrict__ out, float* __restrict__ z_ws, const float* __restrict__ g_ws,
      float* __restrict__ c_ws, float* __restrict__ car_ws, int s)
{
    const int b = blockIdx.x, t = threadIdx.x;
    __shared__ float h2s[HDIM], bufA[512], bufB[512], part[512], d2[256];
    __shared__ float outv[OUTD], nq[QD], sv[95], ov[91], carryL[192], tq[QD], trp[3];
    __shared__ float rvn[3], globn[3], contn[4];

    if (t < 192) carryL[t] = car_ws[b * 192 + t];
    if (t < QD) tq[t] = target_quats[b * QD + t];
    if (t < 3)  trp[t] = target_root_pos[b * 3 + t];
    __syncthreads();

    // LSTM (torch gate order i,f,g,o)
    {
        const float ig = g_ws[b * GDIM + t]        + pred_bias[b * GDIM + t];
        const float fg = g_ws[b * GDIM + 512 + t]  + pred_bias[b * GDIM + 512 + t];
        const float gg = g_ws[b * GDIM + 1024 + t] + pred_bias[b * GDIM + 1024 + t];
        const float og = g_ws[b * GDIM + 1536 + t] + pred_bias[b * GDIM + 1536 + t];
        const float c2 = sig_(fg) * c_ws[b * HDIM + t] + sig_(ig) * tanhf(gg);
        c_ws[b * HDIM + t] = c2;
        const float h2 = sig_(og) * tanhf(c2);
        h2s[t] = h2;
        z_ws[b * ZDIM + 768 + t] = h2;   // h for next step's gate matvec
    }
    __syncthreads();
    // decoder L1 (512 -> 512)
    {
        float acc = de_b1[t];
        #pragma unroll 4
        for (int i = 0; i < 512; ++i) acc = fmaf(h2s[i], de_w1[i * 512 + t], acc);
        bufA[t] = fmaxf(acc, 0.f);
    }
    __syncthreads();
    // decoder L2 (512 -> 256), split-sum across thread halves
    {
        const int j = t & 255, half = t >> 8;
        float acc = 0.f;
        #pragma unroll 4
        for (int i = 0; i < 256; ++i) { const int ii = half * 256 + i;
            acc = fmaf(bufA[ii], de_w2[ii * 256 + j], acc); }
        part[t] = acc;
    }
    __syncthreads();
    if (t < 256) d2[t] = fmaxf(part[t] + part[256 + t] + de_b2[t], 0.f);
    __syncthreads();
    // decoder L3 (256 -> 95)
    if (t < OUTD) {
        float acc = de_b3[t];
        #pragma unroll 4
        for (int i = 0; i < 256; ++i) acc = fmaf(d2[i], de_w3[i * OUTD + t], acc);
        outv[t] = acc;
    }
    __syncthreads();

    // ---- state update ----
    const bool pastS = (s < NPAST);
    if (t < QD) {
        const float qin = pastS ? past_quats[(b * NPAST + s) * QD + t] : carryL[10 + t];
        nq[t] = outv[t] + qin;
    }
    __syncthreads();
    if (t < 22) {
        const float a = nq[4 * t], b2 = nq[4 * t + 1], c3 = nq[4 * t + 2], d4 = nq[4 * t + 3];
        const float inv = 1.f / fmaxf(sqrtf(a * a + b2 * b2 + c3 * c3 + d4 * d4), 1e-12f);
        nq[4 * t] = a * inv; nq[4 * t + 1] = b2 * inv; nq[4 * t + 2] = c3 * inv; nq[4 * t + 3] = d4 * inv;
    }
    if (t < 3) {
        const float rin = pastS ? past_root_vel[(b * NPAST + s) * 3 + t] : carryL[3 + t];
        const float nrv = outv[88 + t] + rin;
        const float g = carryL[t] + (pastS ? rin : nrv);
        rvn[t] = nrv; globn[t] = g;
    }
    if (t < 4) contn[t] = sig_(outv[91 + t]);
    __syncthreads();

    // carry out + frame outputs
    if (t < 3) { car_ws[b * 192 + t] = globn[t]; car_ws[b * 192 + 3 + t] = rvn[t];
                 car_ws[b * 192 + 186 + t] = globn[t] - trp[t]; }
    if (t < 4) car_ws[b * 192 + 6 + t] = contn[t];
    if (t < QD) { car_ws[b * 192 + 10 + t] = nq[t]; car_ws[b * 192 + 98 + t] = nq[t] - tq[t]; }
    if (s == NPAST - 1) {
        const size_t pb = (size_t)b * 30 * 91;
        if (t < 3)  out[pb + t] = rvn[t];
        if (t < QD) out[pb + 3 + t] = nq[t];
        if (t < 4)  out[POSE_ELEMS + (size_t)b * 30 * 4 + t] = contn[t];
    } else if (!pastS) {
        const int k = s - NPAST + 1;
        const size_t pb = ((size_t)b * 30 + k) * 91;
        if (t < 3)  out[pb + t] = globn[t];
        if (t < QD) out[pb + 3 + t] = nq[t];
        if (t < 4)  out[POSE_ELEMS + ((size_t)b * 30 + k) * 4 + t] = contn[t];
    }
    if (s == NSTEPS - 1) return;

    // ---- encoders for step s+1 -> z ----
    const int nx = s + 1;
    if (nx < NPAST) {
        if (t < 4)  sv[t] = past_contacts[(b * NPAST + nx) * 4 + t];
        if (t < QD) { sv[4 + t] = past_quats[(b * NPAST + nx) * QD + t];
                      ov[3 + t] = past_quat_offset[(b * NPAST + nx) * QD + t]; }
        if (t < 3)  { sv[92 + t] = past_root_vel[(b * NPAST + nx) * 3 + t];
                      ov[t]      = past_root_offset[(b * NPAST + nx) * 3 + t]; }
    } else {
        if (t < 4)  sv[t] = contn[t];
        if (t < QD) { sv[4 + t] = nq[t]; ov[3 + t] = nq[t] - tq[t]; }
        if (t < 3)  { sv[92 + t] = rvn[t]; ov[t] = globn[t] - trp[t]; }
    }
    __syncthreads();
    {
        float aS = se_b1[t], aO = oe_b1[t];
        #pragma unroll 4
        for (int i = 0; i < 91; ++i) { aS = fmaf(sv[i], se_w1[i * 512 + t], aS);
                                       aO = fmaf(ov[i], oe_w1[i * 512 + t], aO); }
        #pragma unroll
        for (int i = 91; i < 95; ++i) aS = fmaf(sv[i], se_w1[i * 512 + t], aS);
        bufA[t] = fmaxf(aS, 0.f);
        bufB[t] = fmaxf(aO, 0.f);
    }
    __syncthreads();
    if (t < 256) {
        float a = se_b2[t];
        #pragma unroll 4
        for (int i = 0; i < 512; ++i) a = fmaf(bufA[i], se_w2[i * 256 + t], a);
        z_ws[b * ZDIM + t] = fmaxf(a, 0.f);
    } else {
        const int j = t - 256;
        float a = oe_b2[j];
        #pragma unroll 4
        for (int i = 0; i < 512; ++i) a = fmaf(bufB[i], oe_w2[i * 256 + j], a);
        z_ws[b * ZDIM + 256 + j] = fmaxf(a, 0.f);
    }
}

extern "C" void kernel_launch(void* const* d_in, const int* in_sizes, int n_in,
                              void* d_out, int out_size, void* d_ws, size_t ws_size,
                              hipStream_t stream) {
    const float* prv = (const float*)d_in[0];
    const float* pq  = (const float*)d_in[1];
    const float* pro = (const float*)d_in[2];
    const float* pqo = (const float*)d_in[3];
    const float* pc  = (const float*)d_in[4];
    const float* trp = (const float*)d_in[5];
    const float* tq  = (const float*)d_in[6];
    const float* irp = (const float*)d_in[7];
    const float* pw  = (const float*)d_in[8];
    const float* pb  = (const float*)d_in[9];
    const float* se_w1 = (const float*)d_in[10]; const float* se_b1 = (const float*)d_in[11];
    const float* se_w2 = (const float*)d_in[12]; const float* se_b2 = (const float*)d_in[13];
    const float* oe_w1 = (const float*)d_in[14]; const float* oe_b1 = (const float*)d_in[15];
    const float* oe_w2 = (const float*)d_in[16]; const float* oe_b2 = (const float*)d_in[17];
    const float* te_w1 = (const float*)d_in[18]; const float* te_b1 = (const float*)d_in[19];
    const float* te_w2 = (const float*)d_in[20]; const float* te_b2 = (const float*)d_in[21];
    const float* de_w1 = (const float*)d_in[22]; const float* de_b1 = (const float*)d_in[23];
    const float* de_w2 = (const float*)d_in[24]; const float* de_b2 = (const float*)d_in[25];
    const float* de_w3 = (const float*)d_in[26]; const float* de_b3 = (const float*)d_in[27];
    float* outp = (float*)d_out;

    const size_t WB = (size_t)BATCH * GDIM * ZDIM * 2;              // bf16 weights bytes
    const size_t AUXF = (size_t)BATCH * (ZDIM + GDIM + HDIM + 192); // fp32 aux floats
    const bool bf = ws_size >= WB + AUXF * 4;
    float* aux = bf ? (float*)((char*)d_ws + WB) : (float*)d_ws;
    float* z_ws   = aux;
    float* g_ws   = z_ws + (size_t)BATCH * ZDIM;
    float* c_ws   = g_ws + (size_t)BATCH * GDIM;
    float* car_ws = c_ws + (size_t)BATCH * HDIM;

    if (bf) {
        const int n8 = BATCH * GDIM * (ZDIM / 8);
        conv_bf16<<<dim3(4096), dim3(256), 0, stream>>>((const float4*)pw, (uint4*)d_ws, n8);
    }
    initk<<<dim3(BATCH), dim3(512), 0, stream>>>(prv, pq, pro, pqo, pc, tq, irp,
        se_w1, se_b1, se_w2, se_b2, oe_w1, oe_b1, oe_w2, oe_b2,
        te_w1, te_b1, te_w2, te_b2, z_ws, c_ws, car_ws);
    for (int s = 0; s < NSTEPS; ++s) {
        if (bf) matvec_bf16<<<dim3(BATCH * 32), dim3(256), 0, stream>>>(
                    (const unsigned short*)d_ws, z_ws, g_ws);
        else    matvec_f32<<<dim3(BATCH * 32), dim3(256), 0, stream>>>(pw, z_ws, g_ws);
        stepk<<<dim3(BATCH), dim3(512), 0, stream>>>(prv, pq, pro, pqo, pc, trp, tq, pb,
            se_w1, se_b1, se_w2, se_b2, oe_w1, oe_b1, oe_w2, oe_b2,
            de_w1, de_b1, de_w2, de_b2, de_w3, de_b3,
            outp, z_ws, g_ws, c_ws, car_ws, s);
    }
}

// Round 4
// 6085.272 us; speedup vs baseline: 6.8272x; 1.9928x over previous
//
#include <hip/hip_runtime.h>
#include <hip/hip_bf16.h>
#include <math.h>

#define BATCH 128
#define QD 88
#define HDIM 512
#define ZDIM 1280
#define GDIM 2048
#define NPAST 10
#define NTRANS 29
#define NSTEPS (NPAST + NTRANS)
#define OUTD 95
#define POSE_ELEMS (BATCH * 30 * 91)

typedef float f32x4 __attribute__((ext_vector_type(4)));
typedef unsigned int u32x4 __attribute__((ext_vector_type(4)));

__device__ __forceinline__ float sig_(float x) { return 1.0f / (1.0f + expf(-x)); }
__device__ __forceinline__ float bflo_(unsigned u) { return __uint_as_float(u << 16); }
__device__ __forceinline__ float bfhi_(unsigned u) { return __uint_as_float(u & 0xffff0000u); }

__device__ __forceinline__ void dot8_(const u32x4 wv, const float4 za, const float4 zb,
                                      float& d) {
    d = fmaf(bflo_(wv.x), za.x, d); d = fmaf(bfhi_(wv.x), za.y, d);
    d = fmaf(bflo_(wv.y), za.z, d); d = fmaf(bfhi_(wv.y), za.w, d);
    d = fmaf(bflo_(wv.z), zb.x, d); d = fmaf(bfhi_(wv.z), zb.y, d);
    d = fmaf(bflo_(wv.w), zb.z, d); d = fmaf(bfhi_(wv.w), zb.w, d);
}
__device__ __forceinline__ void dot4_(const uint4 wv, const float4 zv, float& d) {
    const float4 f = *(const float4*)&wv;
    d = fmaf(f.x, zv.x, d); d = fmaf(f.y, zv.y, d);
    d = fmaf(f.z, zv.z, d); d = fmaf(f.w, zv.w, d);
}
__device__ __forceinline__ void fma4_(float4& acc, float x, const float4 w) {
    acc.x = fmaf(x, w.x, acc.x); acc.y = fmaf(x, w.y, acc.y);
    acc.z = fmaf(x, w.z, acc.z); acc.w = fmaf(x, w.w, acc.w);
}

// ---------------- fp32 -> bf16 (RNE) weight conversion, once per call ----------------
__global__ void __launch_bounds__(256)
conv_bf16(const f32x4* __restrict__ in, u32x4* __restrict__ out, int n8)
{
    const int stride = gridDim.x * 256;
    for (int i = blockIdx.x * 256 + threadIdx.x; i < n8; i += stride) {
        const f32x4 a = __builtin_nontemporal_load(in + 2 * i);
        const f32x4 b = __builtin_nontemporal_load(in + 2 * i + 1);
        u32x4 o;
        #define BF_(f) ((__float_as_uint(f) + 0x7fffu + ((__float_as_uint(f) >> 16) & 1u)) >> 16)
        o.x = BF_(a.x) | (BF_(a.y) << 16);
        o.y = BF_(a.z) | (BF_(a.w) << 16);
        o.z = BF_(b.x) | (BF_(b.y) << 16);
        o.w = BF_(b.z) | (BF_(b.w) << 16);
        #undef BF_
        __builtin_nontemporal_store(o, out + i);
    }
}

// ---------------- per-step hypernetwork GEMV, bf16 weights (nontemporal) ----------------
// grid 4096 = 128 samples x 32 chunks; block 256 = 4 waves; wave: 16 rows (8 pairs)
__global__ void __launch_bounds__(256)
matvec_bf16(const unsigned short* __restrict__ W, const float* __restrict__ z_ws,
            const float* __restrict__ pred_bias, float* __restrict__ g_ws)
{
    const int b = blockIdx.x >> 5, chunk = blockIdx.x & 31;
    const int wave = threadIdx.x >> 6, lane = threadIdx.x & 63;
    const int row0 = chunk * 64 + wave * 16;
    const float* zb = z_ws + b * ZDIM;
    const int l8 = lane * 8;
    // bias for this wave's 16 rows, one per lane<16
    const float biasv = (lane < 16) ? pred_bias[b * GDIM + row0 + lane] : 0.f;
    // pair-element idx for slot k = k*512 + lane*8 (mod 1280 for slot 2)
    int e2 = 1024 + l8; if (e2 >= ZDIM) e2 -= ZDIM;
    const float4 zA0 = *(const float4*)(zb + l8),        zB0 = *(const float4*)(zb + l8 + 4);
    const float4 zA1 = *(const float4*)(zb + 512 + l8),  zB1 = *(const float4*)(zb + 512 + l8 + 4);
    const float4 zA2 = *(const float4*)(zb + e2),        zB2 = *(const float4*)(zb + e2 + 4);
    const float4 zA3 = *(const float4*)(zb + 256 + l8),  zB3 = *(const float4*)(zb + 256 + l8 + 4);
    const float4 zA4 = *(const float4*)(zb + 768 + l8),  zB4 = *(const float4*)(zb + 768 + l8 + 4);
    const char* wb = (const char*)W + (size_t)b * GDIM * ZDIM * 2;

    #define ISSUE(p, B) { const char* a_ = wb + (size_t)(row0 + 2 * (p)) * (ZDIM * 2) + lane * 16; \
        B[0] = __builtin_nontemporal_load((const u32x4*)(a_)); \
        B[1] = __builtin_nontemporal_load((const u32x4*)(a_ + 1024)); \
        B[2] = __builtin_nontemporal_load((const u32x4*)(a_ + 2048)); \
        B[3] = __builtin_nontemporal_load((const u32x4*)(a_ + 3072)); \
        B[4] = __builtin_nontemporal_load((const u32x4*)(a_ + 4096)); }

    u32x4 bufa[5], bufb[5];
    ISSUE(0, bufa);
    #pragma unroll
    for (int p = 0; p < 8; ++p) {
        u32x4* cur = (p & 1) ? bufb : bufa;
        u32x4* nxt = (p & 1) ? bufa : bufb;
        if (p < 7) ISSUE(p + 1, nxt);
        float accA = 0.f, accB = 0.f, mid = 0.f;
        dot8_(cur[0], zA0, zB0, accA);
        dot8_(cur[1], zA1, zB1, accA);
        dot8_(cur[2], zA2, zB2, mid);
        dot8_(cur[3], zA3, zB3, accB);
        dot8_(cur[4], zA4, zB4, accB);
        if (lane < 32) accA += mid; else accB += mid;
        float s0 = accA + __shfl_xor(accA, 32);
        float s1 = accB + __shfl_xor(accB, 32);
        float u = (lane < 32) ? s0 : s1;
        #pragma unroll
        for (int m = 16; m >= 1; m >>= 1) u += __shfl_xor(u, m);
        const float badd = __shfl(biasv, 2 * p + ((lane >= 32) ? 1 : 0), 64);
        if (lane == 0)       g_ws[b * GDIM + row0 + 2 * p]     = u + badd;
        else if (lane == 32) g_ws[b * GDIM + row0 + 2 * p + 1] = u + badd;
    }
    #undef ISSUE
}

// ---------------- fp32-weight fallback (only if ws too small for bf16 copy) ----------------
__global__ void __launch_bounds__(256)
matvec_f32(const float* __restrict__ W, const float* __restrict__ z_ws,
           const float* __restrict__ pred_bias, float* __restrict__ g_ws)
{
    const int b = blockIdx.x >> 5, chunk = blockIdx.x & 31;
    const int wave = threadIdx.x >> 6, lane = threadIdx.x & 63;
    const int row0 = chunk * 64 + wave * 16;
    const float* zb = z_ws + b * ZDIM;
    const float biasv = (lane < 16) ? pred_bias[b * GDIM + row0 + lane] : 0.f;
    const int l4 = lane * 4;
    const float4 z0 = *(const float4*)(zb + l4);
    const float4 z1 = *(const float4*)(zb + 256 + l4);
    const float4 z2 = *(const float4*)(zb + 512 + l4);
    const float4 z3 = *(const float4*)(zb + 768 + l4);
    const float4 z4 = *(const float4*)(zb + 1024 + l4);
    const char* wb = (const char*)W + (size_t)b * GDIM * ZDIM * 4;

    #define ISSUE(p, B) { const char* a_ = wb + (size_t)(row0 + 2 * (p)) * (ZDIM * 4) + lane * 16; \
        _Pragma("unroll") for (int i = 0; i < 10; ++i) B[i] = *(const uint4*)(a_ + i * 1024); }

    uint4 bufa[10], bufb[10];
    ISSUE(0, bufa);
    #pragma unroll
    for (int p = 0; p < 8; ++p) {
        uint4* cur = (p & 1) ? bufb : bufa;
        uint4* nxt = (p & 1) ? bufa : bufb;
        if (p < 7) ISSUE(p + 1, nxt);
        float accA = 0.f, accB = 0.f;
        dot4_(cur[0], z0, accA); dot4_(cur[1], z1, accA); dot4_(cur[2], z2, accA);
        dot4_(cur[3], z3, accA); dot4_(cur[4], z4, accA);
        dot4_(cur[5], z0, accB); dot4_(cur[6], z1, accB); dot4_(cur[7], z2, accB);
        dot4_(cur[8], z3, accB); dot4_(cur[9], z4, accB);
        float s0 = accA + __shfl_xor(accA, 32);
        float s1 = accB + __shfl_xor(accB, 32);
        float u = (lane < 32) ? s0 : s1;
        #pragma unroll
        for (int m = 16; m >= 1; m >>= 1) u += __shfl_xor(u, m);
        const float badd = __shfl(biasv, 2 * p + ((lane >= 32) ? 1 : 0), 64);
        if (lane == 0)       g_ws[b * GDIM + row0 + 2 * p]     = u + badd;
        else if (lane == 32) g_ws[b * GDIM + row0 + 2 * p + 1] = u + badd;
    }
    #undef ISSUE
}

// ---------------- init: state=0, h_target, step-0 encoders ----------------
__global__ void __launch_bounds__(512)
initk(const float* __restrict__ past_root_vel, const float* __restrict__ past_quats,
      const float* __restrict__ past_root_offset, const float* __restrict__ past_quat_offset,
      const float* __restrict__ past_contacts, const float* __restrict__ target_quats,
      const float* __restrict__ init_root_pos,
      const float* __restrict__ se_w1, const float* __restrict__ se_b1,
      const float* __restrict__ se_w2, const float* __restrict__ se_b2,
      const float* __restrict__ oe_w1, const float* __restrict__ oe_b1,
      const float* __restrict__ oe_w2, const float* __restrict__ oe_b2,
      const float* __restrict__ te_w1, const float* __restrict__ te_b1,
      const float* __restrict__ te_w2, const float* __restrict__ te_b2,
      float* __restrict__ z_ws, float* __restrict__ c_ws, float* __restrict__ car_ws)
{
    const int b = blockIdx.x, t = threadIdx.x;
    __shared__ float tq[QD], bufA[512], bufB[512], sv[95], ov[91];

    if (t < 192) car_ws[b * 192 + t] = (t < 3) ? init_root_pos[b * 3 + t] : 0.f;
    c_ws[b * HDIM + t] = 0.f;
    z_ws[b * ZDIM + 768 + t] = 0.f;
    if (t < QD) tq[t] = target_quats[b * QD + t];
    if (t < 4)  sv[t] = past_contacts[b * NPAST * 4 + t];
    if (t < QD) { sv[4 + t] = past_quats[b * NPAST * QD + t];
                  ov[3 + t] = past_quat_offset[b * NPAST * QD + t]; }
    if (t < 3)  { sv[92 + t] = past_root_vel[b * NPAST * 3 + t];
                  ov[t]      = past_root_offset[b * NPAST * 3 + t]; }
    __syncthreads();
    {
        float a = te_b1[t];
        #pragma unroll 8
        for (int i = 0; i < QD; ++i) a = fmaf(tq[i], te_w1[i * 512 + t], a);
        bufA[t] = fmaxf(a, 0.f);
    }
    __syncthreads();
    if (t < 256) {
        float a = te_b2[t];
        #pragma unroll 8
        for (int i = 0; i < 512; ++i) a = fmaf(bufA[i], te_w2[i * 256 + t], a);
        z_ws[b * ZDIM + 512 + t] = fmaxf(a, 0.f);
    }
    __syncthreads();
    {
        float aS = se_b1[t], aO = oe_b1[t];
        #pragma unroll 8
        for (int i = 0; i < 91; ++i) { aS = fmaf(sv[i], se_w1[i * 512 + t], aS);
                                       aO = fmaf(ov[i], oe_w1[i * 512 + t], aO); }
        #pragma unroll
        for (int i = 91; i < 95; ++i) aS = fmaf(sv[i], se_w1[i * 512 + t], aS);
        bufA[t] = fmaxf(aS, 0.f);
        bufB[t] = fmaxf(aO, 0.f);
    }
    __syncthreads();
    if (t < 256) {
        float a = se_b2[t];
        #pragma unroll 8
        for (int i = 0; i < 512; ++i) a = fmaf(bufA[i], se_w2[i * 256 + t], a);
        z_ws[b * ZDIM + t] = fmaxf(a, 0.f);
    } else {
        const int j = t - 256;
        float a = oe_b2[j];
        #pragma unroll 8
        for (int i = 0; i < 512; ++i) a = fmaf(bufB[i], oe_w2[i * 256 + j], a);
        z_ws[b * ZDIM + 256 + j] = fmaxf(a, 0.f);
    }
}

// ---------------- per-step: LSTM + decoder + state update + next encoders ----------------
// All GEMVs: float4-along-out x input-slice split, LDS float4 tree reduce.
__global__ void __launch_bounds__(512)
stepk(const float* __restrict__ past_root_vel, const float* __restrict__ past_quats,
      const float* __restrict__ past_root_offset, const float* __restrict__ past_quat_offset,
      const float* __restrict__ past_contacts, const float* __restrict__ target_root_pos,
      const float* __restrict__ target_quats,
      const float* __restrict__ se_w1, const float* __restrict__ se_b1,
      const float* __restrict__ se_w2, const float* __restrict__ se_b2,
      const float* __restrict__ oe_w1, const float* __restrict__ oe_b1,
      const float* __restrict__ oe_w2, const float* __restrict__ oe_b2,
      const float* __restrict__ de_w1, const float* __restrict__ de_b1,
      const float* __restrict__ de_w2, const float* __restrict__ de_b2,
      const float* __restrict__ de_w3, const float* __restrict__ de_b3,
      float* __restrict__ out, float* __restrict__ z_ws, const float* __restrict__ g_ws,
      float* __restrict__ c_ws, float* __restrict__ car_ws, int s)
{
    const int b = blockIdx.x, t = threadIdx.x;
    __shared__ float4 part4[512];                         // 8 KB reduce scratch
    __shared__ __align__(16) float h2s[HDIM], bufA[512], bufB[512], d2[256];
    __shared__ float outv[OUTD], nq[QD], sv[95], ov[91], carryL[192], tq[QD], trp[3];
    __shared__ float rvn[3], globn[3], contn[4];

    if (t < 192) carryL[t] = car_ws[b * 192 + t];
    if (t < QD) tq[t] = target_quats[b * QD + t];
    if (t < 3)  trp[t] = target_root_pos[b * 3 + t];

    // LSTM (bias already folded into g_ws by matvec)
    {
        const float* g = g_ws + b * GDIM;
        const float ig = g[t], fg = g[512 + t], gg = g[1024 + t], og = g[1536 + t];
        const float c2 = sig_(fg) * c_ws[b * HDIM + t] + sig_(ig) * tanhf(gg);
        c_ws[b * HDIM + t] = c2;
        const float h2 = sig_(og) * tanhf(c2);
        h2s[t] = h2;
        z_ws[b * ZDIM + 768 + t] = h2;
    }
    __syncthreads();

    // decoder L1: 512 -> 512.  c = out-group (float4), s = input slice (4 x 128)
    {
        const int c = t & 127, s4 = t >> 7;
        float4 acc = {0.f, 0.f, 0.f, 0.f};
        const float* w = de_w1 + (size_t)(s4 * 128) * 512 + 4 * c;
        #pragma unroll 8
        for (int k = 0; k < 128; ++k)
            fma4_(acc, h2s[s4 * 128 + k], *(const float4*)(w + (size_t)k * 512));
        part4[t] = acc;
    }
    __syncthreads();
    if (t < 128) {
        float4 v = part4[t];
        #pragma unroll
        for (int s4 = 1; s4 < 4; ++s4) { const float4 p = part4[s4 * 128 + t];
            v.x += p.x; v.y += p.y; v.z += p.z; v.w += p.w; }
        const float4 bb = *(const float4*)(de_b1 + 4 * t);
        float4 r; r.x = fmaxf(v.x + bb.x, 0.f); r.y = fmaxf(v.y + bb.y, 0.f);
        r.z = fmaxf(v.z + bb.z, 0.f); r.w = fmaxf(v.w + bb.w, 0.f);
        *(float4*)&bufA[4 * t] = r;
    }
    __syncthreads();

    // decoder L2: 512 -> 256.  64 out-groups x 8 slices of 64
    {
        const int c = t & 63, s8 = t >> 6;
        float4 acc = {0.f, 0.f, 0.f, 0.f};
        const float* w = de_w2 + (size_t)(s8 * 64) * 256 + 4 * c;
        #pragma unroll 8
        for (int k = 0; k < 64; ++k)
            fma4_(acc, bufA[s8 * 64 + k], *(const float4*)(w + (size_t)k * 256));
        part4[t] = acc;
    }
    __syncthreads();
    if (t < 64) {
        float4 v = part4[t];
        #pragma unroll
        for (int s8 = 1; s8 < 8; ++s8) { const float4 p = part4[s8 * 64 + t];
            v.x += p.x; v.y += p.y; v.z += p.z; v.w += p.w; }
        const float4 bb = *(const float4*)(de_b2 + 4 * t);
        float4 r; r.x = fmaxf(v.x + bb.x, 0.f); r.y = fmaxf(v.y + bb.y, 0.f);
        r.z = fmaxf(v.z + bb.z, 0.f); r.w = fmaxf(v.w + bb.w, 0.f);
        *(float4*)&d2[4 * t] = r;
    }
    __syncthreads();

    // decoder L3: 256 -> 95
    if (t < OUTD) {
        float acc = de_b3[t];
        #pragma unroll 16
        for (int i = 0; i < 256; ++i) acc = fmaf(d2[i], de_w3[i * OUTD + t], acc);
        outv[t] = acc;
    }
    __syncthreads();

    // ---- state update ----
    const bool pastS = (s < NPAST);
    if (t < QD) {
        const float qin = pastS ? past_quats[(b * NPAST + s) * QD + t] : carryL[10 + t];
        nq[t] = outv[t] + qin;
    }
    __syncthreads();
    if (t < 22) {
        const float a = nq[4 * t], b2 = nq[4 * t + 1], c3 = nq[4 * t + 2], d4 = nq[4 * t + 3];
        const float inv = 1.f / fmaxf(sqrtf(a * a + b2 * b2 + c3 * c3 + d4 * d4), 1e-12f);
        nq[4 * t] = a * inv; nq[4 * t + 1] = b2 * inv; nq[4 * t + 2] = c3 * inv; nq[4 * t + 3] = d4 * inv;
    }
    if (t < 3) {
        const float rin = pastS ? past_root_vel[(b * NPAST + s) * 3 + t] : carryL[3 + t];
        const float nrv = outv[88 + t] + rin;
        const float g = carryL[t] + (pastS ? rin : nrv);
        rvn[t] = nrv; globn[t] = g;
    }
    if (t < 4) contn[t] = sig_(outv[91 + t]);
    __syncthreads();

    // carry out + frame outputs
    if (t < 3) { car_ws[b * 192 + t] = globn[t]; car_ws[b * 192 + 3 + t] = rvn[t];
                 car_ws[b * 192 + 186 + t] = globn[t] - trp[t]; }
    if (t < 4) car_ws[b * 192 + 6 + t] = contn[t];
    if (t < QD) { car_ws[b * 192 + 10 + t] = nq[t]; car_ws[b * 192 + 98 + t] = nq[t] - tq[t]; }
    if (s == NPAST - 1) {
        const size_t pb = (size_t)b * 30 * 91;
        if (t < 3)  out[pb + t] = rvn[t];
        if (t < QD) out[pb + 3 + t] = nq[t];
        if (t < 4)  out[POSE_ELEMS + (size_t)b * 30 * 4 + t] = contn[t];
    } else if (!pastS) {
        const int k = s - NPAST + 1;
        const size_t pb = ((size_t)b * 30 + k) * 91;
        if (t < 3)  out[pb + t] = globn[t];
        if (t < QD) out[pb + 3 + t] = nq[t];
        if (t < 4)  out[POSE_ELEMS + ((size_t)b * 30 + k) * 4 + t] = contn[t];
    }
    if (s == NSTEPS - 1) return;

    // ---- encoders for step s+1 ----
    const int nx = s + 1;
    if (nx < NPAST) {
        if (t < 4)  sv[t] = past_contacts[(b * NPAST + nx) * 4 + t];
        if (t < QD) { sv[4 + t] = past_quats[(b * NPAST + nx) * QD + t];
                      ov[3 + t] = past_quat_offset[(b * NPAST + nx) * QD + t]; }
        if (t < 3)  { sv[92 + t] = past_root_vel[(b * NPAST + nx) * 3 + t];
                      ov[t]      = past_root_offset[(b * NPAST + nx) * 3 + t]; }
    } else {
        if (t < 4)  sv[t] = contn[t];
        if (t < QD) { sv[4 + t] = nq[t]; ov[3 + t] = nq[t] - tq[t]; }
        if (t < 3)  { sv[92 + t] = rvn[t]; ov[t] = globn[t] - trp[t]; }
    }
    __syncthreads();

    // enc L1 (se & oe concurrently): 128 out-groups x 2 slices, per half-block
    {
        const int tt = t & 255, enc = t >> 8;
        const int c = tt & 127, sl = tt >> 7;
        const float* inp = enc ? ov : sv;
        const float* w1  = enc ? oe_w1 : se_w1;
        const int nin  = enc ? 91 : 95;
        const int half = enc ? 46 : 48;
        const int i0 = sl * half;
        const int iend = (i0 + half < nin) ? (i0 + half) : nin;
        float4 acc = {0.f, 0.f, 0.f, 0.f};
        #pragma unroll 8
        for (int k = 0; k < 48; ++k) {
            const int i = i0 + k;
            if (i < iend) fma4_(acc, inp[i], *(const float4*)(w1 + (size_t)i * 512 + 4 * c));
        }
        part4[enc * 256 + tt] = acc;
    }
    __syncthreads();
    if (t < 128) {
        const float4 a = part4[t], b2 = part4[128 + t];
        const float4 bb = *(const float4*)(se_b1 + 4 * t);
        float4 r; r.x = fmaxf(a.x + b2.x + bb.x, 0.f); r.y = fmaxf(a.y + b2.y + bb.y, 0.f);
        r.z = fmaxf(a.z + b2.z + bb.z, 0.f); r.w = fmaxf(a.w + b2.w + bb.w, 0.f);
        *(float4*)&bufA[4 * t] = r;
    } else if (t < 256) {
        const int c = t - 128;
        const float4 a = part4[256 + c], b2 = part4[384 + c];
        const float4 bb = *(const float4*)(oe_b1 + 4 * c);
        float4 r; r.x = fmaxf(a.x + b2.x + bb.x, 0.f); r.y = fmaxf(a.y + b2.y + bb.y, 0.f);
        r.z = fmaxf(a.z + b2.z + bb.z, 0.f); r.w = fmaxf(a.w + b2.w + bb.w, 0.f);
        *(float4*)&bufB[4 * c] = r;
    }
    __syncthreads();

    // enc L2 (se & oe concurrently): 64 out-groups x 4 slices of 128, per half-block
    {
        const int tt = t & 255, enc = t >> 8;
        const int c = tt & 63, sl = tt >> 6;
        const float* inp = enc ? bufB : bufA;
        const float* w2  = enc ? oe_w2 : se_w2;
        float4 acc = {0.f, 0.f, 0.f, 0.f};
        const float* w = w2 + (size_t)(sl * 128) * 256 + 4 * c;
        #pragma unroll 8
        for (int k = 0; k < 128; ++k)
            fma4_(acc, inp[sl * 128 + k], *(const float4*)(w + (size_t)k * 256));
        part4[enc * 256 + tt] = acc;
    }
    __syncthreads();
    if (t < 64) {
        float4 v = part4[t];
        #pragma unroll
        for (int sl = 1; sl < 4; ++sl) { const float4 p = part4[sl * 64 + t];
            v.x += p.x; v.y += p.y; v.z += p.z; v.w += p.w; }
        const float4 bb = *(const float4*)(se_b2 + 4 * t);
        float4 r; r.x = fmaxf(v.x + bb.x, 0.f); r.y = fmaxf(v.y + bb.y, 0.f);
        r.z = fmaxf(v.z + bb.z, 0.f); r.w = fmaxf(v.w + bb.w, 0.f);
        *(float4*)(z_ws + b * ZDIM + 4 * t) = r;
    } else if (t < 128) {
        const int c = t - 64;
        float4 v = part4[256 + c];
        #pragma unroll
        for (int sl = 1; sl < 4; ++sl) { const float4 p = part4[256 + sl * 64 + c];
            v.x += p.x; v.y += p.y; v.z += p.z; v.w += p.w; }
        const float4 bb = *(const float4*)(oe_b2 + 4 * c);
        float4 r; r.x = fmaxf(v.x + bb.x, 0.f); r.y = fmaxf(v.y + bb.y, 0.f);
        r.z = fmaxf(v.z + bb.z, 0.f); r.w = fmaxf(v.w + bb.w, 0.f);
        *(float4*)(z_ws + b * ZDIM + 256 + 4 * c) = r;
    }
}

extern "C" void kernel_launch(void* const* d_in, const int* in_sizes, int n_in,
                              void* d_out, int out_size, void* d_ws, size_t ws_size,
                              hipStream_t stream) {
    const float* prv = (const float*)d_in[0];
    const float* pq  = (const float*)d_in[1];
    const float* pro = (const float*)d_in[2];
    const float* pqo = (const float*)d_in[3];
    const float* pc  = (const float*)d_in[4];
    const float* trp = (const float*)d_in[5];
    const float* tq  = (const float*)d_in[6];
    const float* irp = (const float*)d_in[7];
    const float* pw  = (const float*)d_in[8];
    const float* pb  = (const float*)d_in[9];
    const float* se_w1 = (const float*)d_in[10]; const float* se_b1 = (const float*)d_in[11];
    const float* se_w2 = (const float*)d_in[12]; const float* se_b2 = (const float*)d_in[13];
    const float* oe_w1 = (const float*)d_in[14]; const float* oe_b1 = (const float*)d_in[15];
    const float* oe_w2 = (const float*)d_in[16]; const float* oe_b2 = (const float*)d_in[17];
    const float* te_w1 = (const float*)d_in[18]; const float* te_b1 = (const float*)d_in[19];
    const float* te_w2 = (const float*)d_in[20]; const float* te_b2 = (const float*)d_in[21];
    const float* de_w1 = (const float*)d_in[22]; const float* de_b1 = (const float*)d_in[23];
    const float* de_w2 = (const float*)d_in[24]; const float* de_b2 = (const float*)d_in[25];
    const float* de_w3 = (const float*)d_in[26]; const float* de_b3 = (const float*)d_in[27];
    float* outp = (float*)d_out;

    const size_t WB = (size_t)BATCH * GDIM * ZDIM * 2;              // bf16 weights bytes
    const size_t AUXF = (size_t)BATCH * (ZDIM + GDIM + HDIM + 192); // fp32 aux floats
    const bool bf = ws_size >= WB + AUXF * 4;
    float* aux = bf ? (float*)((char*)d_ws + WB) : (float*)d_ws;
    float* z_ws   = aux;
    float* g_ws   = z_ws + (size_t)BATCH * ZDIM;
    float* c_ws   = g_ws + (size_t)BATCH * GDIM;
    float* car_ws = c_ws + (size_t)BATCH * HDIM;

    if (bf) {
        const int n8 = BATCH * GDIM * (ZDIM / 8);
        conv_bf16<<<dim3(4096), dim3(256), 0, stream>>>((const f32x4*)pw, (u32x4*)d_ws, n8);
    }
    initk<<<dim3(BATCH), dim3(512), 0, stream>>>(prv, pq, pro, pqo, pc, tq, irp,
        se_w1, se_b1, se_w2, se_b2, oe_w1, oe_b1, oe_w2, oe_b2,
        te_w1, te_b1, te_w2, te_b2, z_ws, c_ws, car_ws);
    for (int s = 0; s < NSTEPS; ++s) {
        if (bf) matvec_bf16<<<dim3(BATCH * 32), dim3(256), 0, stream>>>(
                    (const unsigned short*)d_ws, z_ws, pb, g_ws);
        else    matvec_f32<<<dim3(BATCH * 32), dim3(256), 0, stream>>>(pw, z_ws, pb, g_ws);
        stepk<<<dim3(BATCH), dim3(512), 0, stream>>>(prv, pq, pro, pqo, pc, trp, tq,
            se_w1, se_b1, se_w2, se_b2, oe_w1, oe_b1, oe_w2, oe_b2,
            de_w1, de_b1, de_w2, de_b2, de_w3, de_b3,
            outp, z_ws, g_ws, c_ws, car_ws, s);
    }
}